// Round 20
// baseline (71.701 us; speedup 1.0000x reference)
//
#include <hip/hip_runtime.h>
#include <hip/hip_bf16.h>

#define B_ 32
#define D_ 512
#define N_ 1024
#define M_ 1024
#define BT 256
#define BK 64
#define NIT 16            // 2 tiles x 8 K-steps, continuous

typedef __attribute__((ext_vector_type(8))) short bf16x8;
typedef __attribute__((ext_vector_type(4))) float f32x4;
typedef __attribute__((ext_vector_type(4))) int   i32x4;
typedef unsigned short ushort_t;

__device__ __forceinline__ unsigned map_f(float f) {
    unsigned b = __float_as_uint(f);
    return (b & 0x80000000u) ? ~b : (b | 0x80000000u);
}

// ============================================================================
// Fused fp32->bf16 GEMM-max: persistent 2-tile blocks (R19 structure) with
// the R2-VERIFIED LDS layout (zero measured bank conflicts):
//   tile [j=256][k=64] bf16, rows 128B = 8 granules of 16B;
//   granule q of row j at byte j*128 + 16*(q ^ (j&7)).
// Staging: thread t holds rows k=8q..8q+7 (q=t&7), cols jg*4..+3 (jg=t>>3);
// loads are 8x dwordx4 (128B-coalesced per row); in-register 4x8 transpose
// (16 cvt_pk) then 4x b128 writes (R2 pattern: conflict-free).
// Fragments: plain b128 reads at j*128 + 16*((4kk+l4)^(j&7)) -- R2-verified
// read pattern, compiler-scheduled (no asm / sched_barrier / setprio).
// ============================================================================
struct __align__(16) GSmem {
    ushort_t As[2][BT * BK];   // 32KB each: As[0]@0, As[1]@32768
    ushort_t Bs[2][BT * BK];   // Bs[0]@65536, Bs[1]@98304
    float red[8];
};

// Load 8 rows x 4 cols fp32: fl[dd] = row (k0+8q+dd), col jg*4.
__device__ __forceinline__ void load_tile(const float* __restrict__ p, int k0,
                                          int q, int jg, float4* fl) {
    const float* base = p + (size_t)(k0 + q * 8) * N_ + jg * 4;
    #pragma unroll
    for (int dd = 0; dd < 8; ++dd)
        fl[dd] = *reinterpret_cast<const float4*>(base + (size_t)dd * N_);
}

// Transpose in reg + write [j][k]: for each of 4 j's, pack 8 k's -> b128.
__device__ __forceinline__ void flush_tile(char* lds, int q, int jg, const float4* fl) {
    #pragma unroll
    for (int ji = 0; ji < 4; ++ji) {
        const int j = jg * 4 + ji;
        __hip_bfloat162 h0 = __float22bfloat162_rn(
            make_float2(reinterpret_cast<const float*>(&fl[0])[ji],
                        reinterpret_cast<const float*>(&fl[1])[ji]));
        __hip_bfloat162 h1 = __float22bfloat162_rn(
            make_float2(reinterpret_cast<const float*>(&fl[2])[ji],
                        reinterpret_cast<const float*>(&fl[3])[ji]));
        __hip_bfloat162 h2 = __float22bfloat162_rn(
            make_float2(reinterpret_cast<const float*>(&fl[4])[ji],
                        reinterpret_cast<const float*>(&fl[5])[ji]));
        __hip_bfloat162 h3 = __float22bfloat162_rn(
            make_float2(reinterpret_cast<const float*>(&fl[6])[ji],
                        reinterpret_cast<const float*>(&fl[7])[ji]));
        i32x4 v = { *reinterpret_cast<const int*>(&h0), *reinterpret_cast<const int*>(&h1),
                    *reinterpret_cast<const int*>(&h2), *reinterpret_cast<const int*>(&h3) };
        *reinterpret_cast<i32x4*>(lds + j * 128 + 16 * (q ^ (j & 7))) = v;
    }
}

__global__ __launch_bounds__(512, 2)
void fused_gemm_max_kernel(const float* __restrict__ e1, const float* __restrict__ e2,
                           float* __restrict__ out) {
    __shared__ GSmem sm;
    const int wg  = blockIdx.x;
    const int swz = (wg & 7) * 32 + (wg >> 3);   // XCD swizzle (256 % 8 == 0)
    const int b    = swz >> 3;                   // 8 tile-pairs per batch
    const int pair = swz & 7;
    const int tn  = (pair >> 1) * BT;            // shared A panel
    const int tc0 = (pair & 1) * 512;            // B panels: tc0, tc0+256

    const int t    = threadIdx.x;
    const int lane = t & 63;
    const int wave = t >> 6;
    const int wrow = (wave >> 2) * 128;          // A j-offset
    const int wcol = (wave & 3) * 64;            // B j-offset

    // staging geometry (R2 pattern scaled to 512 threads)
    const int q  = t & 7;
    const int jg = t >> 3;                       // 0..63

    // fragment geometry (R2-verified): j = base + m*16 + l15, gran = (4kk+l4)^(j&7)
    const int l15 = lane & 15;
    const int l4  = lane >> 4;
    unsigned uA[8], uB[4];
    #pragma unroll
    for (int m = 0; m < 8; ++m) {
        const int j = wrow + m * 16 + l15;
        uA[m] = (unsigned)(j * 128 + 16 * (l4 ^ (j & 7)));
    }
    #pragma unroll
    for (int n = 0; n < 4; ++n) {
        const int j = wcol + n * 16 + l15;
        uB[n] = (unsigned)(65536 + j * 128 + 16 * (l4 ^ (j & 7)));
    }
    const char* ldsb = (const char*)&sm.As[0][0];

    const float* Ap  = e1 + (size_t)b * D_ * N_ + tn;
    const float* Bp0 = e2 + (size_t)b * D_ * M_ + tc0;
    const float* Bp1 = Bp0 + BT;

    f32x4 acc[8][4] = {};
    float4 fl[8];
    float tmax = -3.4e38f;

    // Prologue (once for both tiles).
    load_tile(Ap, 0, q, jg, fl);
    flush_tile((char*)sm.As[0], q, jg, fl);
    load_tile(Bp0, 0, q, jg, fl);
    flush_tile((char*)sm.Bs[0], q, jg, fl);
    load_tile(Ap, BK, q, jg, fl);
    asm volatile("s_waitcnt lgkmcnt(0)" ::: "memory");
    __builtin_amdgcn_s_barrier();

    int cur = 0;
    #pragma unroll 1
    for (int it = 0; it < NIT; ++it) {
        const unsigned off = (unsigned)cur * 32768u;
        const bool has_next = (it < NIT - 1);

        #pragma unroll
        for (int kk = 0; kk < 2; ++kk) {
            const unsigned kx = (unsigned)(kk << 6);   // granule bit2: addr ^ 64
            bf16x8 af[8], bf[4];
            #pragma unroll
            for (int m = 0; m < 8; ++m)
                af[m] = *reinterpret_cast<const bf16x8*>(ldsb + off + (uA[m] ^ kx));
            #pragma unroll
            for (int n = 0; n < 4; ++n)
                bf[n] = *reinterpret_cast<const bf16x8*>(ldsb + off + (uB[n] ^ kx));
            #pragma unroll
            for (int m = 0; m < 8; ++m)
                #pragma unroll
                for (int n = 0; n < 4; ++n)
                    acc[m][n] = __builtin_amdgcn_mfma_f32_16x16x32_bf16(
                        af[m], bf[n], acc[m][n], 0, 0, 0);

            // Time-shared staging between the two MFMA clusters:
            if (kk == 0 && has_next) {
                flush_tile((char*)sm.As[cur ^ 1], q, jg, fl);     // A(it+1) -> LDS
                const float* bp = (it + 1 < 8) ? Bp0 : Bp1;
                load_tile(bp, ((it + 1) & 7) * BK, q, jg, fl);    // issue B(it+1)
            }
        }

        // Tile boundary: fold tile 0 into tmax, reset accumulator.
        if (it == 7) {
            #pragma unroll
            for (int m = 0; m < 8; ++m)
                #pragma unroll
                for (int n = 0; n < 4; ++n) {
                    #pragma unroll
                    for (int i = 0; i < 4; ++i)
                        tmax = fmaxf(tmax, acc[m][n][i]);
                    acc[m][n] = f32x4{0.f, 0.f, 0.f, 0.f};
                }
        }

        if (has_next) {
            flush_tile((char*)sm.Bs[cur ^ 1], q, jg, fl);         // B(it+1) -> LDS
            if (it < NIT - 2)
                load_tile(Ap, ((it + 2) & 7) * BK, q, jg, fl);    // issue A(it+2)
        }
        asm volatile("s_waitcnt lgkmcnt(0)" ::: "memory");        // ds ops drained
        __builtin_amdgcn_s_barrier();
        cur ^= 1;
    }

    // Fold tile 1; wave + block reduce; one atomic per block.
    #pragma unroll
    for (int m = 0; m < 8; ++m)
        #pragma unroll
        for (int n = 0; n < 4; ++n)
            #pragma unroll
            for (int i = 0; i < 4; ++i)
                tmax = fmaxf(tmax, acc[m][n][i]);
    #pragma unroll
    for (int off2 = 32; off2; off2 >>= 1)
        tmax = fmaxf(tmax, __shfl_xor(tmax, off2));
    if (lane == 0) sm.red[wave] = tmax;
    __syncthreads();
    if (t == 0) {
        float m8 = sm.red[0];
        #pragma unroll
        for (int w = 1; w < 8; ++w) m8 = fmaxf(m8, sm.red[w]);
        atomicMax(reinterpret_cast<unsigned*>(out) + b, map_f(m8));
    }
}

__global__ void finalize_kernel(float* out) {
    const int i = threadIdx.x;
    unsigned u = reinterpret_cast<unsigned*>(out)[i];
    out[i] = __uint_as_float((u & 0x80000000u) ? (u ^ 0x80000000u) : ~u);
}

extern "C" void kernel_launch(void* const* d_in, const int* in_sizes, int n_in,
                              void* d_out, int out_size, void* d_ws, size_t ws_size,
                              hipStream_t stream) {
    const float* e1 = (const float*)d_in[0];
    const float* e2 = (const float*)d_in[1];
    float* out = (float*)d_out;

    (void)hipMemsetAsync(d_out, 0, B_ * sizeof(float), stream);  // 0 == -inf under map_f

    fused_gemm_max_kernel<<<dim3(256), 512, 0, stream>>>(e1, e2, out);
    finalize_kernel<<<1, B_, 0, stream>>>(out);
}

// Round 21
// 50.843 us; speedup vs baseline: 1.4102x; 1.4102x over previous
//
#include <hip/hip_runtime.h>
#include <hip/hip_bf16.h>

#define B_ 32
#define D_ 512
#define N_ 1024
#define M_ 1024
#define BT 256
#define BK 64
#define NIT 16            // 2 tiles x 8 K-steps, continuous

typedef __attribute__((ext_vector_type(8))) short bf16x8;
typedef __attribute__((ext_vector_type(4))) short s16x4;
typedef __attribute__((ext_vector_type(4))) float f32x4;
typedef __attribute__((ext_vector_type(4))) int   i32x4;
typedef unsigned short ushort_t;

__device__ __forceinline__ unsigned map_f(float f) {
    unsigned b = __float_as_uint(f);
    return (b & 0x80000000u) ? ~b : (b | 0x80000000u);
}

// ============================================================================
// Fused fp32->bf16 GEMM-max: PERSISTENT 2-tile blocks == R19 verbatim
// (empirical best, 51.1 us). Final structure ledger:
//  - R20 [j][k] zero-conflict layout: -40% (staging loads degrade to 128B
//    segments @4KB stride -- the R3/R4 L2-channel poison). tr_read bank
//    conflicts (3.1M, ~9%) are NOT on the critical path; load pattern is.
//  - R13/R15 counted-wait manual pipelines: -12..-18% (defeat compiler sched).
//  - R16 32x32 MFMA: -4%. R18 builtin/compiler-scheduled reads: null.
//  - R9-R11 occupancy pushes: regress (registers saturated: 128 acc AGPR
//    + 124 arch = 252/256 per wave).
// Grid 256 = 1 block/CU; each block: two 256x256 tiles sharing one A panel,
// one continuous 16-iter K-loop (one prologue, dbuf rolls across boundary).
// LDS [k=64][j=256] bf16, granule gr of row k at k*512 + 16*(gr^(2*(k&3)));
// b128 writes (R8-verified), asm ds_read_b64_tr_b16 fragment reads
// (R5-verified); one 32-reg staging buffer time-shared A/B.
// ============================================================================
struct __align__(16) GSmem {
    ushort_t As[2][BT * BK];   // 32KB each: As[0]@0, As[1]@32768
    ushort_t Bs[2][BT * BK];   // Bs[0]@65536, Bs[1]@98304
    float red[8];
};

__device__ __forceinline__ void load_tile(const float* __restrict__ p, int k0,
                                          int krb, int gr, float4* fl) {
    #pragma unroll
    for (int it = 0; it < 4; ++it) {
        const float* q = p + (size_t)(k0 + krb + it) * N_ + gr * 8;
        fl[2 * it]     = *reinterpret_cast<const float4*>(q);
        fl[2 * it + 1] = *reinterpret_cast<const float4*>(q + 4);
    }
}

__device__ __forceinline__ void flush_tile(char* lds, int krb, int gr, const float4* fl) {
    #pragma unroll
    for (int it = 0; it < 4; ++it) {
        const int k = krb + it;
        const float4& f0 = fl[2 * it];
        const float4& f1 = fl[2 * it + 1];
        __hip_bfloat162 h0 = __float22bfloat162_rn(make_float2(f0.x, f0.y));
        __hip_bfloat162 h1 = __float22bfloat162_rn(make_float2(f0.z, f0.w));
        __hip_bfloat162 h2 = __float22bfloat162_rn(make_float2(f1.x, f1.y));
        __hip_bfloat162 h3 = __float22bfloat162_rn(make_float2(f1.z, f1.w));
        i32x4 v = { *reinterpret_cast<const int*>(&h0), *reinterpret_cast<const int*>(&h1),
                    *reinterpret_cast<const int*>(&h2), *reinterpret_cast<const int*>(&h3) };
        *reinterpret_cast<i32x4*>(lds + k * 512 + 16 * (gr ^ (2 * (k & 3)))) = v;
    }
}

__global__ __launch_bounds__(512, 2)
void fused_gemm_max_kernel(const float* __restrict__ e1, const float* __restrict__ e2,
                           float* __restrict__ out) {
    __shared__ GSmem sm;
    const int wg  = blockIdx.x;
    const int swz = (wg & 7) * 32 + (wg >> 3);   // XCD swizzle (256 % 8 == 0)
    const int b    = swz >> 3;                   // 8 tile-pairs per batch
    const int pair = swz & 7;
    const int tn  = (pair >> 1) * BT;            // shared A panel
    const int tc0 = (pair & 1) * 512;            // B panels: tc0, tc0+256

    const int t    = threadIdx.x;
    const int lane = t & 63;
    const int wave = t >> 6;
    const int wrow = (wave >> 2) * 128;
    const int wcol = (wave & 3) * 64;

    const int krb = (t >> 5) * 4;
    const int gr  = t & 31;

    // tr_read per-lane geometry (R5-verified pattern, stride scaled to 512B)
    const int c = lane & 15, g = lane >> 4;
    const int r = c >> 2, d = (c >> 1) & 1, h = c & 1;

    unsigned tbA[8], tbB[4];
    #pragma unroll
    for (int m = 0; m < 8; ++m)
        tbA[m] = (unsigned)((8 * g + r) * 512
               + 16 * ((((wrow >> 3) + 2 * m + d) ^ (2 * r))) + 8 * h);
    #pragma unroll
    for (int n = 0; n < 4; ++n)
        tbB[n] = (unsigned)(65536 + (8 * g + r) * 512
               + 16 * ((((wcol >> 3) + 2 * n + d) ^ (2 * r))) + 8 * h);
    const unsigned ldsbase = (unsigned)(uintptr_t)&sm.As[0][0];

    const float* Ap  = e1 + (size_t)b * D_ * N_ + tn;
    const float* Bp0 = e2 + (size_t)b * D_ * M_ + tc0;
    const float* Bp1 = Bp0 + BT;

    f32x4 acc[8][4] = {};
    float4 fl[8];
    float tmax = -3.4e38f;

    // Prologue (once for both tiles): A0 -> LDS0, B0 -> LDS0, issue A(1) loads.
    load_tile(Ap, 0, krb, gr, fl);
    flush_tile((char*)sm.As[0], krb, gr, fl);
    load_tile(Bp0, 0, krb, gr, fl);
    flush_tile((char*)sm.Bs[0], krb, gr, fl);
    load_tile(Ap, BK, krb, gr, fl);
    asm volatile("s_waitcnt lgkmcnt(0)" ::: "memory");
    __builtin_amdgcn_s_barrier();

    int cur = 0;
    #pragma unroll 1
    for (int it = 0; it < NIT; ++it) {
        const unsigned off = ldsbase + (unsigned)cur * 32768u;
        const bool has_next = (it < NIT - 1);

        #pragma unroll
        for (int kk = 0; kk < 2; ++kk) {
            s16x4 alo[8], ahi[8], blo[4], bhi[4];
            #pragma unroll
            for (int m = 0; m < 8; ++m) {
                asm volatile("ds_read_b64_tr_b16 %0, %1 offset:%2"
                             : "=v"(alo[m]) : "v"(tbA[m] + off), "n"(kk * 16384));
                asm volatile("ds_read_b64_tr_b16 %0, %1 offset:%2"
                             : "=v"(ahi[m]) : "v"(tbA[m] + off), "n"(kk * 16384 + 2048));
            }
            #pragma unroll
            for (int n = 0; n < 4; ++n) {
                asm volatile("ds_read_b64_tr_b16 %0, %1 offset:%2"
                             : "=v"(blo[n]) : "v"(tbB[n] + off), "n"(kk * 16384));
                asm volatile("ds_read_b64_tr_b16 %0, %1 offset:%2"
                             : "=v"(bhi[n]) : "v"(tbB[n] + off), "n"(kk * 16384 + 2048));
            }
            asm volatile("s_waitcnt lgkmcnt(0)" ::: "memory");
            __builtin_amdgcn_sched_barrier(0);
            bf16x8 af[8], bf[4];
            #pragma unroll
            for (int m = 0; m < 8; ++m)
                af[m] = __builtin_shufflevector(alo[m], ahi[m], 0, 1, 2, 3, 4, 5, 6, 7);
            #pragma unroll
            for (int n = 0; n < 4; ++n)
                bf[n] = __builtin_shufflevector(blo[n], bhi[n], 0, 1, 2, 3, 4, 5, 6, 7);
            __builtin_amdgcn_s_setprio(1);
            #pragma unroll
            for (int m = 0; m < 8; ++m)
                #pragma unroll
                for (int n = 0; n < 4; ++n)
                    acc[m][n] = __builtin_amdgcn_mfma_f32_16x16x32_bf16(
                        af[m], bf[n], acc[m][n], 0, 0, 0);
            __builtin_amdgcn_s_setprio(0);

            // Time-shared staging between the two MFMA clusters:
            if (kk == 0 && has_next) {
                flush_tile((char*)sm.As[cur ^ 1], krb, gr, fl);   // A(it+1) -> LDS
                const float* bp = (it + 1 < 8) ? Bp0 : Bp1;
                load_tile(bp, ((it + 1) & 7) * BK, krb, gr, fl);  // issue B(it+1)
            }
        }

        // Tile boundary: fold tile 0 into tmax, reset accumulator.
        if (it == 7) {
            #pragma unroll
            for (int m = 0; m < 8; ++m)
                #pragma unroll
                for (int n = 0; n < 4; ++n) {
                    #pragma unroll
                    for (int i = 0; i < 4; ++i)
                        tmax = fmaxf(tmax, acc[m][n][i]);
                    acc[m][n] = f32x4{0.f, 0.f, 0.f, 0.f};
                }
        }

        if (has_next) {
            flush_tile((char*)sm.Bs[cur ^ 1], krb, gr, fl);       // B(it+1) -> LDS
            if (it < NIT - 2)
                load_tile(Ap, ((it + 2) & 7) * BK, krb, gr, fl);  // issue A(it+2)
        }
        asm volatile("s_waitcnt lgkmcnt(0)" ::: "memory");        // ds_writes drained
        __builtin_amdgcn_s_barrier();
        cur ^= 1;
    }

    // Fold tile 1; wave + block reduce; one atomic per block (both tiles same b).
    #pragma unroll
    for (int m = 0; m < 8; ++m)
        #pragma unroll
        for (int n = 0; n < 4; ++n)
            #pragma unroll
            for (int i = 0; i < 4; ++i)
                tmax = fmaxf(tmax, acc[m][n][i]);
    #pragma unroll
    for (int off2 = 32; off2; off2 >>= 1)
        tmax = fmaxf(tmax, __shfl_xor(tmax, off2));
    if (lane == 0) sm.red[wave] = tmax;
    __syncthreads();
    if (t == 0) {
        float m8 = sm.red[0];
        #pragma unroll
        for (int w = 1; w < 8; ++w) m8 = fmaxf(m8, sm.red[w]);
        atomicMax(reinterpret_cast<unsigned*>(out) + b, map_f(m8));
    }
}

__global__ void finalize_kernel(float* out) {
    const int i = threadIdx.x;
    unsigned u = reinterpret_cast<unsigned*>(out)[i];
    out[i] = __uint_as_float((u & 0x80000000u) ? (u ^ 0x80000000u) : ~u);
}

extern "C" void kernel_launch(void* const* d_in, const int* in_sizes, int n_in,
                              void* d_out, int out_size, void* d_ws, size_t ws_size,
                              hipStream_t stream) {
    const float* e1 = (const float*)d_in[0];
    const float* e2 = (const float*)d_in[1];
    float* out = (float*)d_out;

    (void)hipMemsetAsync(d_out, 0, B_ * sizeof(float), stream);  // 0 == -inf under map_f

    fused_gemm_max_kernel<<<dim3(256), 512, 0, stream>>>(e1, e2, out);
    finalize_kernel<<<1, B_, 0, stream>>>(out);
}